// Round 1
// baseline (327.198 us; speedup 1.0000x reference)
//
#include <hip/hip_runtime.h>
#include <stdint.h>

#define S_LEN 4096
#define D_MOD 1024
#define NH    16
#define EH    64

typedef short bf16x8 __attribute__((ext_vector_type(8)));
typedef float f32x4  __attribute__((ext_vector_type(4)));

__device__ __forceinline__ unsigned short f2b(float x){
    uint32_t u = __float_as_uint(x);
    u = (u + 0x7fffu + ((u >> 16) & 1u)) >> 16;   // RNE f32->bf16
    return (unsigned short)u;
}

// ---------------- conversion kernels ----------------

__global__ void k_conv_x(const float* __restrict__ x, unsigned short* __restrict__ xb, int n){
    int i = (blockIdx.x * blockDim.x + threadIdx.x) * 4;
    if (i < n){
        float4 v = *(const float4*)(x + i);
        ushort4 o;
        o.x = f2b(v.x); o.y = f2b(v.y); o.z = f2b(v.z); o.w = f2b(v.w);
        *(ushort4*)(xb + i) = o;
    }
}

// wt[n][d], n = t*1024 + h*64 + e  (row n = column (h,e) of W_t), bf16
__global__ void k_conv_w(const float* __restrict__ Wq, const float* __restrict__ Wk,
                         const float* __restrict__ Wv, unsigned short* __restrict__ wt){
    int idx = blockIdx.x * 256 + threadIdx.x;       // exact: 3072*1024 threads
    int n = idx >> 10, d = idx & 1023;
    int t = n >> 10, h = (n >> 6) & 15, e = n & 63;
    const float* W = (t == 0) ? Wq : ((t == 1) ? Wk : Wv);
    wt[idx] = f2b(W[(size_t)((h << 10) + d) * 64 + e]);
}

// wot[d][he] = Wo[he][d], bf16
__global__ void k_conv_wo(const float* __restrict__ Wo, unsigned short* __restrict__ wot){
    int idx = blockIdx.x * 256 + threadIdx.x;       // exact: 1024*1024
    int d = idx >> 10, he = idx & 1023;
    wot[idx] = f2b(Wo[(size_t)(he << 10) + d]);
}

// ---------------- GEMM: C[M,N] = A[M,K] * B[N,K]^T  (both row-major bf16) ----------------
// MODE 0: QKV projection epilogue (scatter to q/k/vT + bias)
// MODE 1: output projection epilogue (f32 out + bo)

template<int MODE>
__global__ void k_gemm(const unsigned short* __restrict__ A, const unsigned short* __restrict__ B, int K,
                       unsigned short* __restrict__ qb, unsigned short* __restrict__ kb,
                       unsigned short* __restrict__ vb,
                       const float* __restrict__ b0, const float* __restrict__ b1, const float* __restrict__ b2,
                       float* __restrict__ outp, const float* __restrict__ bo){
    __shared__ uint4 lsA4[512];    // 64 rows x 128B, XOR-swizzled
    __shared__ uint4 lsB4[512];
    char* lsA = (char*)lsA4;
    char* lsB = (char*)lsB4;
    const int tid = threadIdx.x;
    const int lane = tid & 63, w = tid >> 6;
    const int lr = lane & 15, lg = lane >> 4;
    const int wm = w >> 1, wn = w & 1;             // 2x2 wave grid, 32x32 per wave
    const int m0 = blockIdx.y * 64, n0 = blockIdx.x * 64;

    f32x4 acc[2][2] = {};

    for (int k0 = 0; k0 < K; k0 += 64){
        __syncthreads();
        #pragma unroll
        for (int i = 0; i < 2; i++){
            int idx = tid + 256 * i;               // 512 chunks of 16B per tile
            int row = idx >> 3, c16 = idx & 7;
            uint4 va = *(const uint4*)(A + (size_t)(m0 + row) * K + k0 + c16 * 8);
            *(uint4*)(lsA + row * 128 + ((c16 * 16) ^ ((row & 7) << 4))) = va;
            uint4 vbv = *(const uint4*)(B + (size_t)(n0 + row) * K + k0 + c16 * 8);
            *(uint4*)(lsB + row * 128 + ((c16 * 16) ^ ((row & 7) << 4))) = vbv;
        }
        __syncthreads();
        #pragma unroll
        for (int kc = 0; kc < 2; kc++){
            bf16x8 af[2], bfr[2];
            #pragma unroll
            for (int mi = 0; mi < 2; mi++){
                int row = wm * 32 + mi * 16 + lr;
                af[mi] = *(const bf16x8*)(lsA + row * 128 + ((kc * 64 + lg * 16) ^ ((row & 7) << 4)));
            }
            #pragma unroll
            for (int ni = 0; ni < 2; ni++){
                int row = wn * 32 + ni * 16 + lr;
                bfr[ni] = *(const bf16x8*)(lsB + row * 128 + ((kc * 64 + lg * 16) ^ ((row & 7) << 4)));
            }
            #pragma unroll
            for (int mi = 0; mi < 2; mi++)
                #pragma unroll
                for (int ni = 0; ni < 2; ni++)
                    acc[mi][ni] = __builtin_amdgcn_mfma_f32_16x16x32_bf16(af[mi], bfr[ni], acc[mi][ni], 0, 0, 0);
        }
    }

    // epilogue: D layout col = lane&15 (n), row = (lane>>4)*4 + reg (m)
    #pragma unroll
    for (int mi = 0; mi < 2; mi++){
        #pragma unroll
        for (int ni = 0; ni < 2; ni++){
            int gnb = n0 + wn * 32 + ni * 16;
            if (MODE == 0){
                int t = gnb >> 10, h = (gnb >> 6) & 15;
                int e = (gnb & 63) + lr;
                const float* bp = (t == 0) ? b0 : ((t == 1) ? b1 : b2);
                float badd = bp[(h << 6) + e];
                #pragma unroll
                for (int r = 0; r < 4; r++){
                    int gm = m0 + wm * 32 + mi * 16 + lg * 4 + r;
                    unsigned short val = f2b(acc[mi][ni][r] + badd);
                    if (t == 0)       qb[((size_t)((h << 12) + gm) << 6) + e] = val;
                    else if (t == 1)  kb[((size_t)((h << 12) + gm) << 6) + e] = val;
                    else              vb[(size_t)((h << 6) + e) * 4096 + gm] = val;  // v transposed [h][e][s]
                }
            } else {
                int gn = gnb + lr;
                float badd = bo[gn];
                #pragma unroll
                for (int r = 0; r < 4; r++){
                    int gm = m0 + wm * 32 + mi * 16 + lg * 4 + r;
                    outp[(size_t)gm * 1024 + gn] = acc[mi][ni][r] + badd;
                }
            }
        }
    }
}

// ---------------- flash attention ----------------
// grid (S/64, H); block 256 = 4 waves; wave w owns 16 q-rows.
// q/k: [H][S][E] bf16; v: [H][E][S] bf16; out ob: [S][H*E] bf16.

__global__ void k_attn(const unsigned short* __restrict__ qb, const unsigned short* __restrict__ kb,
                       const unsigned short* __restrict__ vb, const float* __restrict__ scale,
                       unsigned short* __restrict__ ob){
    __shared__ uint4 lsK4[512];    // 64 keys x 64 e  (swizzled rows)
    __shared__ uint4 lsV4[512];    // 64 e    x 64 keys (swizzled rows)
    __shared__ uint4 lsP4[512];    // 4 waves x (16 rows x 64 keys)
    char* lsK = (char*)lsK4;
    char* lsV = (char*)lsV4;
    char* lsP = (char*)lsP4;

    const int tid = threadIdx.x;
    const int lane = tid & 63, w = tid >> 6, lr = lane & 15, lg = lane >> 4;
    const int h = blockIdx.y;
    const int q0 = blockIdx.x * 64 + w * 16;
    const float sc_h = scale[h];
    char* myP = lsP + w * 2048;

    bf16x8 qf[2];
    #pragma unroll
    for (int c = 0; c < 2; c++)
        qf[c] = *(const bf16x8*)(qb + (size_t)((h << 12) + q0 + lr) * 64 + c * 32 + lg * 8);

    f32x4 oacc[4] = {};
    float m_run[4], l_run[4];
    #pragma unroll
    for (int r = 0; r < 4; r++){ m_run[r] = -1e30f; l_run[r] = 0.f; }

    for (int kt = 0; kt < S_LEN; kt += 64){
        __syncthreads();
        #pragma unroll
        for (int i = 0; i < 2; i++){
            int idx = tid + 256 * i;
            int row = idx >> 3, c16 = idx & 7;
            uint4 kv = *(const uint4*)(kb + (size_t)((h << 12) + kt + row) * 64 + c16 * 8);
            *(uint4*)(lsK + row * 128 + ((c16 * 16) ^ ((row & 7) << 4))) = kv;
            uint4 vv = *(const uint4*)(vb + (size_t)((h << 6) + row) * 4096 + kt + c16 * 8);
            *(uint4*)(lsV + row * 128 + ((c16 * 16) ^ ((row & 7) << 4))) = vv;
        }
        __syncthreads();

        // S-tiles: scores[q=lr.. via D-layout][key]
        f32x4 sv[4];
        #pragma unroll
        for (int nt = 0; nt < 4; nt++){
            f32x4 s = {};
            #pragma unroll
            for (int kc = 0; kc < 2; kc++){
                int row = nt * 16 + lr;
                bf16x8 kf = *(const bf16x8*)(lsK + row * 128 + ((kc * 64 + lg * 16) ^ ((row & 7) << 4)));
                s = __builtin_amdgcn_mfma_f32_16x16x32_bf16(qf[kc], kf, s, 0, 0, 0);
            }
            sv[nt] = s * sc_h;
        }

        // online softmax per owned row (reg r -> row lg*4+r), reduce over 16 lanes (key dim)
        #pragma unroll
        for (int r = 0; r < 4; r++){
            float mx = fmaxf(fmaxf(sv[0][r], sv[1][r]), fmaxf(sv[2][r], sv[3][r]));
            #pragma unroll
            for (int off = 1; off < 16; off <<= 1)
                mx = fmaxf(mx, __shfl_xor(mx, off, 64));
            float mnew = fmaxf(m_run[r], mx);
            float corr = __expf(m_run[r] - mnew);
            m_run[r] = mnew;
            float psum = 0.f;
            #pragma unroll
            for (int nt = 0; nt < 4; nt++){
                float p = __expf(sv[nt][r] - mnew);
                sv[nt][r] = p;
                psum += p;
            }
            #pragma unroll
            for (int off = 1; off < 16; off <<= 1)
                psum += __shfl_xor(psum, off, 64);
            l_run[r] = l_run[r] * corr + psum;
            #pragma unroll
            for (int et = 0; et < 4; et++) oacc[et][r] *= corr;
            // store P row to wave-private LDS (swizzled, bf16)
            int prow = lg * 4 + r;
            #pragma unroll
            for (int nt = 0; nt < 4; nt++){
                int key = nt * 16 + lr;
                *(unsigned short*)(myP + prow * 128 + ((key * 2) ^ ((prow & 7) << 4))) = f2b(sv[nt][r]);
            }
        }

        // PV: A = P (rows=q-local), B = Vt rows (col=e, k=key)
        bf16x8 pf[2];
        #pragma unroll
        for (int kc = 0; kc < 2; kc++)
            pf[kc] = *(const bf16x8*)(myP + lr * 128 + ((kc * 64 + lg * 16) ^ ((lr & 7) << 4)));
        #pragma unroll
        for (int et = 0; et < 4; et++){
            #pragma unroll
            for (int kc = 0; kc < 2; kc++){
                int row = et * 16 + lr;
                bf16x8 vf = *(const bf16x8*)(lsV + row * 128 + ((kc * 64 + lg * 16) ^ ((row & 7) << 4)));
                oacc[et] = __builtin_amdgcn_mfma_f32_16x16x32_bf16(pf[kc], vf, oacc[et], 0, 0, 0);
            }
        }
    }

    // normalize + store O (bf16) to ob[s][h*64+e]
    #pragma unroll
    for (int et = 0; et < 4; et++){
        #pragma unroll
        for (int r = 0; r < 4; r++){
            int row = q0 + lg * 4 + r;
            int col = (h << 6) + et * 16 + lr;
            ob[(size_t)row * 1024 + col] = f2b(oacc[et][r] / l_run[r]);
        }
    }
}

// ---------------- launcher ----------------

extern "C" void kernel_launch(void* const* d_in, const int* in_sizes, int n_in,
                              void* d_out, int out_size, void* d_ws, size_t ws_size,
                              hipStream_t stream){
    const float* x  = (const float*)d_in[0];
    const float* Wq = (const float*)d_in[1];
    const float* bq = (const float*)d_in[2];
    const float* Wk = (const float*)d_in[3];
    const float* bk = (const float*)d_in[4];
    const float* Wv = (const float*)d_in[5];
    const float* bv = (const float*)d_in[6];
    const float* sc = (const float*)d_in[7];
    const float* Wo = (const float*)d_in[8];
    const float* bo = (const float*)d_in[9];
    float* out = (float*)d_out;
    char* ws = (char*)d_ws;
    const size_t MB = 1u << 20;

    unsigned short* xb  = (unsigned short*)(ws + 0);        // 8 MB  [S][D] bf16
    unsigned short* ob  = xb;                               // alias: o reuses xb after GEMM1
    unsigned short* wt  = (unsigned short*)(ws + 8  * MB);  // 6 MB  [3072][1024]
    unsigned short* wot = (unsigned short*)(ws + 14 * MB);  // 2 MB  [1024][1024]
    unsigned short* qb  = (unsigned short*)(ws + 16 * MB);  // 8 MB  [H][S][E]
    unsigned short* kb  = (unsigned short*)(ws + 24 * MB);  // 8 MB  [H][S][E]
    unsigned short* vb  = (unsigned short*)(ws + 32 * MB);  // 8 MB  [H][E][S]

    k_conv_x <<<4096,  256, 0, stream>>>(x, xb, S_LEN * D_MOD);
    k_conv_w <<<12288, 256, 0, stream>>>(Wq, Wk, Wv, wt);
    k_conv_wo<<<4096,  256, 0, stream>>>(Wo, wot);

    k_gemm<0><<<dim3(48, 64), 256, 0, stream>>>(xb, wt, D_MOD, qb, kb, vb, bq, bk, bv, nullptr, nullptr);
    k_attn   <<<dim3(64, 16), 256, 0, stream>>>(qb, kb, vb, sc, ob);
    k_gemm<1><<<dim3(16, 64), 256, 0, stream>>>(ob, wot, D_MOD, nullptr, nullptr, nullptr,
                                                nullptr, nullptr, nullptr, out, bo);
}

// Round 2
// 247.499 us; speedup vs baseline: 1.3220x; 1.3220x over previous
//
#include <hip/hip_runtime.h>
#include <stdint.h>

#define S_LEN 4096
#define D_MOD 1024
#define NH    16
#define EH    64

typedef short bf16x8 __attribute__((ext_vector_type(8)));
typedef float f32x4  __attribute__((ext_vector_type(4)));
typedef float f32x16 __attribute__((ext_vector_type(16)));

__device__ __forceinline__ unsigned short f2b(float x){
    uint32_t u = __float_as_uint(x);
    u = (u + 0x7fffu + ((u >> 16) & 1u)) >> 16;   // RNE f32->bf16
    return (unsigned short)u;
}

__device__ __forceinline__ uint32_t cvtpk_bf16(float lo, float hi){
    uint32_t r;
    asm volatile("v_cvt_pk_bf16_f32 %0, %1, %2" : "=v"(r) : "v"(lo), "v"(hi));
    return r;
}

// ---------------- conversion kernels ----------------

__global__ void k_conv_x(const float* __restrict__ x, unsigned short* __restrict__ xb, int n){
    int i = (blockIdx.x * blockDim.x + threadIdx.x) * 4;
    if (i < n){
        float4 v = *(const float4*)(x + i);
        ushort4 o;
        o.x = f2b(v.x); o.y = f2b(v.y); o.z = f2b(v.z); o.w = f2b(v.w);
        *(ushort4*)(xb + i) = o;
    }
}

// wt[n][d], n = t*1024 + h*64 + e  (row n = column (h,e) of W_t), bf16
__global__ void k_conv_w(const float* __restrict__ Wq, const float* __restrict__ Wk,
                         const float* __restrict__ Wv, unsigned short* __restrict__ wt){
    int idx = blockIdx.x * 256 + threadIdx.x;       // exact: 3072*1024 threads
    int n = idx >> 10, d = idx & 1023;
    int t = n >> 10, h = (n >> 6) & 15, e = n & 63;
    const float* W = (t == 0) ? Wq : ((t == 1) ? Wk : Wv);
    wt[idx] = f2b(W[(size_t)((h << 10) + d) * 64 + e]);
}

// wot[d][he] = Wo[he][d], bf16
__global__ void k_conv_wo(const float* __restrict__ Wo, unsigned short* __restrict__ wot){
    int idx = blockIdx.x * 256 + threadIdx.x;       // exact: 1024*1024
    int d = idx >> 10, he = idx & 1023;
    wot[idx] = f2b(Wo[(size_t)(he << 10) + d]);
}

// ---------------- GEMM: C[M,N] = A[M,K] * B[N,K]^T  (both row-major bf16) ----------------

template<int MODE>
__global__ void k_gemm(const unsigned short* __restrict__ A, const unsigned short* __restrict__ B, int K,
                       unsigned short* __restrict__ qb, unsigned short* __restrict__ kb,
                       unsigned short* __restrict__ vb,
                       const float* __restrict__ b0, const float* __restrict__ b1, const float* __restrict__ b2,
                       float* __restrict__ outp, const float* __restrict__ bo){
    __shared__ uint4 lsA4[512];    // 64 rows x 128B, XOR-swizzled
    __shared__ uint4 lsB4[512];
    char* lsA = (char*)lsA4;
    char* lsB = (char*)lsB4;
    const int tid = threadIdx.x;
    const int lane = tid & 63, w = tid >> 6;
    const int lr = lane & 15, lg = lane >> 4;
    const int wm = w >> 1, wn = w & 1;             // 2x2 wave grid, 32x32 per wave
    const int m0 = blockIdx.y * 64, n0 = blockIdx.x * 64;

    f32x4 acc[2][2] = {};

    for (int k0 = 0; k0 < K; k0 += 64){
        __syncthreads();
        #pragma unroll
        for (int i = 0; i < 2; i++){
            int idx = tid + 256 * i;               // 512 chunks of 16B per tile
            int row = idx >> 3, c16 = idx & 7;
            uint4 va = *(const uint4*)(A + (size_t)(m0 + row) * K + k0 + c16 * 8);
            *(uint4*)(lsA + row * 128 + ((c16 * 16) ^ ((row & 7) << 4))) = va;
            uint4 vbv = *(const uint4*)(B + (size_t)(n0 + row) * K + k0 + c16 * 8);
            *(uint4*)(lsB + row * 128 + ((c16 * 16) ^ ((row & 7) << 4))) = vbv;
        }
        __syncthreads();
        #pragma unroll
        for (int kc = 0; kc < 2; kc++){
            bf16x8 af[2], bfr[2];
            #pragma unroll
            for (int mi = 0; mi < 2; mi++){
                int row = wm * 32 + mi * 16 + lr;
                af[mi] = *(const bf16x8*)(lsA + row * 128 + ((kc * 64 + lg * 16) ^ ((row & 7) << 4)));
            }
            #pragma unroll
            for (int ni = 0; ni < 2; ni++){
                int row = wn * 32 + ni * 16 + lr;
                bfr[ni] = *(const bf16x8*)(lsB + row * 128 + ((kc * 64 + lg * 16) ^ ((row & 7) << 4)));
            }
            #pragma unroll
            for (int mi = 0; mi < 2; mi++)
                #pragma unroll
                for (int ni = 0; ni < 2; ni++)
                    acc[mi][ni] = __builtin_amdgcn_mfma_f32_16x16x32_bf16(af[mi], bfr[ni], acc[mi][ni], 0, 0, 0);
        }
    }

    // epilogue: D layout col = lane&15 (n), row = (lane>>4)*4 + reg (m)
    #pragma unroll
    for (int mi = 0; mi < 2; mi++){
        #pragma unroll
        for (int ni = 0; ni < 2; ni++){
            int gnb = n0 + wn * 32 + ni * 16;
            if (MODE == 0){
                int t = gnb >> 10, h = (gnb >> 6) & 15;
                int e = (gnb & 63) + lr;
                const float* bp = (t == 0) ? b0 : ((t == 1) ? b1 : b2);
                float badd = bp[(h << 6) + e];
                #pragma unroll
                for (int r = 0; r < 4; r++){
                    int gm = m0 + wm * 32 + mi * 16 + lg * 4 + r;
                    unsigned short val = f2b(acc[mi][ni][r] + badd);
                    if (t == 0)       qb[((size_t)((h << 12) + gm) << 6) + e] = val;
                    else if (t == 1)  kb[((size_t)((h << 12) + gm) << 6) + e] = val;
                    else              vb[(size_t)((h << 6) + e) * 4096 + gm] = val;  // v transposed [h][e][s]
                }
            } else {
                int gn = gnb + lr;
                float badd = bo[gn];
                #pragma unroll
                for (int r = 0; r < 4; r++){
                    int gm = m0 + wm * 32 + mi * 16 + lg * 4 + r;
                    outp[(size_t)gm * 1024 + gn] = acc[mi][ni][r] + badd;
                }
            }
        }
    }
}

// ---------------- flash attention, 32x32 swapped-QK^T, in-register softmax ----------------
// grid (S/128, H); block 256 = 4 waves; wave w owns 32 q-rows.
// q/k: [H][S][E] bf16; v: [H][E][S] bf16; out ob: [S][H*E] bf16.
//
// QK^T: mfma(A=K, B=Q) -> S^T[key][q]; lane (q=lane&31, hi=lane>>5) holds, per 32-key tile,
//   p[r] = P[q][key=(r&3)+8*(r>>2)+4*hi] (r=0..15) -> full row in the lane pair (l, l^32).
// PV:  mfma(A=Vt, B=P) -> O^T[e][q]; softmax stats (per q=lane&31) are lane-uniform.

__global__ void k_attn(const unsigned short* __restrict__ qb, const unsigned short* __restrict__ kb,
                       const unsigned short* __restrict__ vb, const float* __restrict__ scale,
                       unsigned short* __restrict__ ob){
    __shared__ uint4 lsK4[512];    // 64 keys x 64 e  (swizzled rows)
    __shared__ uint4 lsV4[512];    // 64 e    x 64 keys (swizzled rows)
    char* lsK = (char*)lsK4;
    char* lsV = (char*)lsV4;

    const int tid = threadIdx.x;
    const int lane = tid & 63, w = tid >> 6;
    const int ql = lane & 31, hi = lane >> 5;
    const int h = blockIdx.y;
    const int q0 = blockIdx.x * 128 + w * 32;
    const float sc2 = scale[h] * 1.4426950408889634f;   // fold log2(e): exp -> exp2

    // Q fragments (B-operand): lane needs Q[q0+ql][e = kc*16 + hi*8 + j]
    bf16x8 qf[4];
    #pragma unroll
    for (int kc = 0; kc < 4; kc++)
        qf[kc] = *(const bf16x8*)(qb + (size_t)((h << 12) + q0 + ql) * 64 + kc * 16 + hi * 8);

    f32x16 oacc[2] = {};           // O^T: lane holds O[e = et*32 + crow(r,hi)][q = q0+ql]
    float m_run = -1e30f, l_run = 0.f;

    for (int kt = 0; kt < S_LEN; kt += 64){
        __syncthreads();
        #pragma unroll
        for (int i = 0; i < 2; i++){
            int idx = tid + 256 * i;               // 512 chunks of 16B per tile
            int row = idx >> 3, c16 = idx & 7;
            uint4 kv = *(const uint4*)(kb + (size_t)((h << 12) + kt + row) * 64 + c16 * 8);
            *(uint4*)(lsK + row * 128 + ((c16 * 16) ^ ((row & 7) << 4))) = kv;
            uint4 vv = *(const uint4*)(vb + (size_t)((h << 6) + row) * 4096 + kt + c16 * 8);
            *(uint4*)(lsV + row * 128 + ((c16 * 16) ^ ((row & 7) << 4))) = vv;
        }
        __syncthreads();

        // ---- QK^T (swapped): s[kt2] = K_tile^T ... D[key][q]
        f32x16 s[2];
        #pragma unroll
        for (int kt2 = 0; kt2 < 2; kt2++){
            f32x16 sx = {};
            #pragma unroll
            for (int kc = 0; kc < 4; kc++){
                int row = kt2 * 32 + ql;
                bf16x8 kf = *(const bf16x8*)(lsK + row * 128 + ((kc * 32 + hi * 16) ^ ((row & 7) << 4)));
                sx = __builtin_amdgcn_mfma_f32_32x32x16_bf16(kf, qf[kc], sx, 0, 0, 0);
            }
            s[kt2] = sx * sc2;
        }

        // ---- online softmax, fully in-register (row = q = lane&31, shared with lane^32)
        float mx = -1e30f;
        #pragma unroll
        for (int kt2 = 0; kt2 < 2; kt2++)
            #pragma unroll
            for (int r = 0; r < 16; r++)
                mx = fmaxf(mx, s[kt2][r]);
        mx = fmaxf(mx, __shfl_xor(mx, 32, 64));
        float mnew = fmaxf(m_run, mx);
        float corr = __builtin_amdgcn_exp2f(m_run - mnew);
        m_run = mnew;

        float psum = 0.f;
        #pragma unroll
        for (int kt2 = 0; kt2 < 2; kt2++)
            #pragma unroll
            for (int r = 0; r < 16; r++){
                float p = __builtin_amdgcn_exp2f(s[kt2][r] - mnew);
                s[kt2][r] = p;
                psum += p;
            }
        psum += __shfl_xor(psum, 32, 64);
        l_run = l_run * corr + psum;
        oacc[0] *= corr;
        oacc[1] *= corr;

        // ---- pack P -> bf16 B-fragments pa[ks]: lane needs P[q][key = 16*ks + 8*hi + j]
        // own regs give 4 of each 8-key run; partner lane (l^32) has the other 4.
        bf16x8 pa[4];
        #pragma unroll
        for (int kt2 = 0; kt2 < 2; kt2++){
            #pragma unroll
            for (int c = 0; c < 2; c++){
                int base = 8 * c;
                uint32_t a0 = cvtpk_bf16(s[kt2][base + 0], s[kt2][base + 1]);
                uint32_t a1 = cvtpk_bf16(s[kt2][base + 2], s[kt2][base + 3]);
                uint32_t b0 = cvtpk_bf16(s[kt2][base + 4], s[kt2][base + 5]);
                uint32_t b1 = cvtpk_bf16(s[kt2][base + 6], s[kt2][base + 7]);
                uint32_t sa0 = (uint32_t)__shfl_xor((int)a0, 32, 64);
                uint32_t sa1 = (uint32_t)__shfl_xor((int)a1, 32, 64);
                uint32_t sb0 = (uint32_t)__shfl_xor((int)b0, 32, 64);
                uint32_t sb1 = (uint32_t)__shfl_xor((int)b1, 32, 64);
                uint32_t w0 = hi ? sb0 : a0;   // j=0..1
                uint32_t w1 = hi ? sb1 : a1;   // j=2..3
                uint32_t w2 = hi ? b0 : sa0;   // j=4..5
                uint32_t w3 = hi ? b1 : sa1;   // j=6..7
                uint32_t frag[4] = {w0, w1, w2, w3};
                pa[kt2 * 2 + c] = *(bf16x8*)frag;
            }
        }

        // ---- PV: O^T[et] += sum_ks mfma(A=Vt(et,ks), B=pa[ks])
        #pragma unroll
        for (int et = 0; et < 2; et++){
            #pragma unroll
            for (int ks = 0; ks < 4; ks++){
                int row = et * 32 + ql;
                bf16x8 vf = *(const bf16x8*)(lsV + row * 128 + ((ks * 32 + hi * 16) ^ ((row & 7) << 4)));
                oacc[et] = __builtin_amdgcn_mfma_f32_32x32x16_bf16(vf, pa[ks], oacc[et], 0, 0, 0);
            }
        }
    }

    // ---- normalize + store: lane q = q0+ql; e = et*32 + 8g + 4hi + m (m=0..3 contiguous)
    float inv = 1.0f / l_run;
    #pragma unroll
    for (int et = 0; et < 2; et++){
        #pragma unroll
        for (int g = 0; g < 4; g++){
            ushort4 o4;
            o4.x = f2b(oacc[et][4 * g + 0] * inv);
            o4.y = f2b(oacc[et][4 * g + 1] * inv);
            o4.z = f2b(oacc[et][4 * g + 2] * inv);
            o4.w = f2b(oacc[et][4 * g + 3] * inv);
            int e = et * 32 + 8 * g + 4 * hi;
            *(ushort4*)(ob + (size_t)(q0 + ql) * 1024 + (h << 6) + e) = o4;
        }
    }
}

// ---------------- launcher ----------------

extern "C" void kernel_launch(void* const* d_in, const int* in_sizes, int n_in,
                              void* d_out, int out_size, void* d_ws, size_t ws_size,
                              hipStream_t stream){
    const float* x  = (const float*)d_in[0];
    const float* Wq = (const float*)d_in[1];
    const float* bq = (const float*)d_in[2];
    const float* Wk = (const float*)d_in[3];
    const float* bk = (const float*)d_in[4];
    const float* Wv = (const float*)d_in[5];
    const float* bv = (const float*)d_in[6];
    const float* sc = (const float*)d_in[7];
    const float* Wo = (const float*)d_in[8];
    const float* bo = (const float*)d_in[9];
    float* out = (float*)d_out;
    char* ws = (char*)d_ws;
    const size_t MB = 1u << 20;

    unsigned short* xb  = (unsigned short*)(ws + 0);        // 8 MB  [S][D] bf16
    unsigned short* ob  = xb;                               // alias: o reuses xb after GEMM1
    unsigned short* wt  = (unsigned short*)(ws + 8  * MB);  // 6 MB  [3072][1024]
    unsigned short* wot = (unsigned short*)(ws + 14 * MB);  // 2 MB  [1024][1024]
    unsigned short* qb  = (unsigned short*)(ws + 16 * MB);  // 8 MB  [H][S][E]
    unsigned short* kb  = (unsigned short*)(ws + 24 * MB);  // 8 MB  [H][S][E]
    unsigned short* vb  = (unsigned short*)(ws + 32 * MB);  // 8 MB  [H][E][S]

    k_conv_x <<<4096,  256, 0, stream>>>(x, xb, S_LEN * D_MOD);
    k_conv_w <<<12288, 256, 0, stream>>>(Wq, Wk, Wv, wt);
    k_conv_wo<<<4096,  256, 0, stream>>>(Wo, wot);

    k_gemm<0><<<dim3(48, 64), 256, 0, stream>>>(xb, wt, D_MOD, qb, kb, vb, bq, bk, bv, nullptr, nullptr);
    k_attn   <<<dim3(32, 16), 256, 0, stream>>>(qb, kb, vb, sc, ob);
    k_gemm<1><<<dim3(16, 64), 256, 0, stream>>>(ob, wot, D_MOD, nullptr, nullptr, nullptr,
                                                nullptr, nullptr, nullptr, out, bo);
}

// Round 3
// 225.256 us; speedup vs baseline: 1.4526x; 1.0987x over previous
//
#include <hip/hip_runtime.h>
#include <stdint.h>

#define S_LEN 4096
#define D_MOD 1024
#define NH    16
#define EH    64

typedef short bf16x8 __attribute__((ext_vector_type(8)));
typedef float f32x4  __attribute__((ext_vector_type(4)));
typedef float f32x16 __attribute__((ext_vector_type(16)));

__device__ __forceinline__ unsigned short f2b(float x){
    uint32_t u = __float_as_uint(x);
    u = (u + 0x7fffu + ((u >> 16) & 1u)) >> 16;   // RNE f32->bf16
    return (unsigned short)u;
}

__device__ __forceinline__ uint32_t cvtpk_bf16(float lo, float hi){
    uint32_t r;
    asm volatile("v_cvt_pk_bf16_f32 %0, %1, %2" : "=v"(r) : "v"(lo), "v"(hi));
    return r;
}

__device__ __forceinline__ void gld_lds16(const void* g, void* l){
    __builtin_amdgcn_global_load_lds((const __attribute__((address_space(1))) void*)g,
                                     (__attribute__((address_space(3))) void*)l, 16, 0, 0);
}

// ---------------- conversion kernels ----------------

__global__ void k_conv_x(const float* __restrict__ x, unsigned short* __restrict__ xb, int n){
    int i = (blockIdx.x * blockDim.x + threadIdx.x) * 4;
    if (i < n){
        float4 v = *(const float4*)(x + i);
        ushort4 o;
        o.x = f2b(v.x); o.y = f2b(v.y); o.z = f2b(v.z); o.w = f2b(v.w);
        *(ushort4*)(xb + i) = o;
    }
}

// wt[n][d], n = t*1024 + h*64 + e  (row n = column (h,e) of W_t), bf16
__global__ void k_conv_w(const float* __restrict__ Wq, const float* __restrict__ Wk,
                         const float* __restrict__ Wv, unsigned short* __restrict__ wt){
    int idx = blockIdx.x * 256 + threadIdx.x;       // exact: 3072*1024 threads
    int n = idx >> 10, d = idx & 1023;
    int t = n >> 10, h = (n >> 6) & 15, e = n & 63;
    const float* W = (t == 0) ? Wq : ((t == 1) ? Wk : Wv);
    wt[idx] = f2b(W[(size_t)((h << 10) + d) * 64 + e]);
}

// wot[d][he] = Wo[he][d], bf16
__global__ void k_conv_wo(const float* __restrict__ Wo, unsigned short* __restrict__ wot){
    int idx = blockIdx.x * 256 + threadIdx.x;       // exact: 1024*1024
    int d = idx >> 10, he = idx & 1023;
    wot[idx] = f2b(Wo[(size_t)(he << 10) + d]);
}

// ---------------- GEMM: C[M,N] = A[M,K] * B[N,K]^T  (both row-major bf16) ----------------
// MODE 0: QKV projection epilogue (scatter to q/k/vT + bias; q pre-scaled by scale[h]*log2e)
// MODE 1: output projection epilogue (f32 out + bo)

template<int MODE>
__global__ void k_gemm(const unsigned short* __restrict__ A, const unsigned short* __restrict__ B, int K,
                       unsigned short* __restrict__ qb, unsigned short* __restrict__ kb,
                       unsigned short* __restrict__ vb,
                       const float* __restrict__ b0, const float* __restrict__ b1, const float* __restrict__ b2,
                       const float* __restrict__ scl,
                       float* __restrict__ outp, const float* __restrict__ bo){
    __shared__ uint4 lsA4[512];    // 64 rows x 128B, XOR-swizzled
    __shared__ uint4 lsB4[512];
    char* lsA = (char*)lsA4;
    char* lsB = (char*)lsB4;
    const int tid = threadIdx.x;
    const int lane = tid & 63, w = tid >> 6;
    const int lr = lane & 15, lg = lane >> 4;
    const int wm = w >> 1, wn = w & 1;             // 2x2 wave grid, 32x32 per wave
    const int m0 = blockIdx.y * 64, n0 = blockIdx.x * 64;

    f32x4 acc[2][2] = {};

    for (int k0 = 0; k0 < K; k0 += 64){
        __syncthreads();
        #pragma unroll
        for (int i = 0; i < 2; i++){
            int idx = tid + 256 * i;               // 512 chunks of 16B per tile
            int row = idx >> 3, c16 = idx & 7;
            uint4 va = *(const uint4*)(A + (size_t)(m0 + row) * K + k0 + c16 * 8);
            *(uint4*)(lsA + row * 128 + ((c16 * 16) ^ ((row & 7) << 4))) = va;
            uint4 vbv = *(const uint4*)(B + (size_t)(n0 + row) * K + k0 + c16 * 8);
            *(uint4*)(lsB + row * 128 + ((c16 * 16) ^ ((row & 7) << 4))) = vbv;
        }
        __syncthreads();
        #pragma unroll
        for (int kc = 0; kc < 2; kc++){
            bf16x8 af[2], bfr[2];
            #pragma unroll
            for (int mi = 0; mi < 2; mi++){
                int row = wm * 32 + mi * 16 + lr;
                af[mi] = *(const bf16x8*)(lsA + row * 128 + ((kc * 64 + lg * 16) ^ ((row & 7) << 4)));
            }
            #pragma unroll
            for (int ni = 0; ni < 2; ni++){
                int row = wn * 32 + ni * 16 + lr;
                bfr[ni] = *(const bf16x8*)(lsB + row * 128 + ((kc * 64 + lg * 16) ^ ((row & 7) << 4)));
            }
            #pragma unroll
            for (int mi = 0; mi < 2; mi++)
                #pragma unroll
                for (int ni = 0; ni < 2; ni++)
                    acc[mi][ni] = __builtin_amdgcn_mfma_f32_16x16x32_bf16(af[mi], bfr[ni], acc[mi][ni], 0, 0, 0);
        }
    }

    // epilogue: D layout col = lane&15 (n), row = (lane>>4)*4 + reg (m)
    #pragma unroll
    for (int mi = 0; mi < 2; mi++){
        #pragma unroll
        for (int ni = 0; ni < 2; ni++){
            int gnb = n0 + wn * 32 + ni * 16;
            if (MODE == 0){
                int t = gnb >> 10, h = (gnb >> 6) & 15;
                int e = (gnb & 63) + lr;
                const float* bp = (t == 0) ? b0 : ((t == 1) ? b1 : b2);
                float badd = bp[(h << 6) + e];
                float qs = (t == 0) ? scl[h] * 1.4426950408889634f : 1.0f;
                #pragma unroll
                for (int r = 0; r < 4; r++){
                    int gm = m0 + wm * 32 + mi * 16 + lg * 4 + r;
                    if (t == 0)       qb[((size_t)((h << 12) + gm) << 6) + e] = f2b((acc[mi][ni][r] + badd) * qs);
                    else if (t == 1)  kb[((size_t)((h << 12) + gm) << 6) + e] = f2b(acc[mi][ni][r] + badd);
                    else              vb[(size_t)((h << 6) + e) * 4096 + gm] = f2b(acc[mi][ni][r] + badd);  // [h][e][s]
                }
            } else {
                int gn = gnb + lr;
                float badd = bo[gn];
                #pragma unroll
                for (int r = 0; r < 4; r++){
                    int gm = m0 + wm * 32 + mi * 16 + lg * 4 + r;
                    outp[(size_t)gm * 1024 + gn] = acc[mi][ni][r] + badd;
                }
            }
        }
    }
}

// ---------------- flash attention, 32x32 swapped-QK^T, fragment-major LDS, 2-phase pipeline ---
// grid (32, 16); block 256 = 4 waves; wave w owns 32 q-rows (block = 128 q); KVBLK = 128.
// q (pre-scaled by scale*log2e) / k: [H][S][E] bf16; v: [H][E][S] bf16; ob: [S][H*E] bf16.
//
// LDS fragment-major: K slot = kt2*256 + kc*64 + lane -> holds K[kt+kt2*32+(l&31)][kc*16+(l>>5)*8 +:8]
//                     V slot = et*512 + ks*64 + lane  -> holds Vt[et*32+(l&31)][kt+ks*16+(l>>5)*8 +:8]
// Reads are lane-linear (conflict-free); staging via global_load_lds (per-lane src, linear dest).

__global__ void k_attn(const unsigned short* __restrict__ qb, const unsigned short* __restrict__ kb,
                       const unsigned short* __restrict__ vb, unsigned short* __restrict__ ob){
    __shared__ uint4 ldsb[4096];   // 64 KB: [buf2][ K 16KB | V 16KB ]
    char* ldsc = (char*)ldsb;

    const int tid = threadIdx.x;
    const int lane = tid & 63, w = tid >> 6;
    const int ql = lane & 31, hi = lane >> 5;

    int wg = blockIdx.y * 32 + blockIdx.x;
    wg = (wg & 7) * 64 + (wg >> 3);            // XCD-bijective swizzle (512 % 8 == 0)
    const int h = wg >> 5;
    const int q0 = (wg & 31) * 128 + w * 32;

    // Q fragments (B-operand): lane needs Q[q0+ql][e = kc*16 + hi*8 + j]; scale pre-folded.
    bf16x8 qf[4];
    #pragma unroll
    for (int kc = 0; kc < 4; kc++)
        qf[kc] = *(const bf16x8*)(qb + (size_t)((h << 12) + q0 + ql) * 64 + kc * 16 + hi * 8);

    f32x16 oacc[2] = {};           // O^T: lane holds O[e = et*32 + crow(r,hi)][q = q0+ql]
    float m_run = -1e30f, l_run = 0.f;

    const int et_s = w >> 1;                    // this wave's V staging rows
    const int ksb_s = (w & 1) * 64;             // and key-col base (elements)

    auto stage = [&](int buf, int kt){
        char* Kd = ldsc + buf * 32768;
        char* Vd = Kd + 16384;
        const unsigned short* ksrc = kb + ((size_t)(h << 12) + kt + w * 32 + ql) * 64 + hi * 8;
        const unsigned short* vsrc = vb + (size_t)((h << 6) + et_s * 32 + ql) * 4096 + kt + ksb_s + hi * 8;
        #pragma unroll
        for (int c = 0; c < 4; c++){
            gld_lds16(ksrc + c * 16, Kd + (w * 256 + c * 64) * 16);
            gld_lds16(vsrc + c * 16, Vd + (w * 256 + c * 64) * 16);
        }
    };

    stage(0, 0);
    __syncthreads();               // drains vmcnt before barrier

    int buf = 0;
    for (int t = 0; t < 32; t++){
        if (t < 31) stage(buf ^ 1, (t + 1) * 128);

        const char* Kc = ldsc + buf * 32768;
        const char* Vc = Kc + 16384;

        // ---- QK^T (swapped): s[kt2] = D[key][q], scores already in log2 domain
        f32x16 s[4];
        #pragma unroll
        for (int kt2 = 0; kt2 < 4; kt2++){
            f32x16 sx = {};
            #pragma unroll
            for (int kc = 0; kc < 4; kc++){
                bf16x8 kf = *(const bf16x8*)(Kc + kt2 * 4096 + kc * 1024 + lane * 16);
                sx = __builtin_amdgcn_mfma_f32_32x32x16_bf16(kf, qf[kc], sx, 0, 0, 0);
            }
            s[kt2] = sx;
        }

        // ---- online softmax, in-register (row q = lane&31, half-row shared with lane^32)
        float mx = -1e30f;
        #pragma unroll
        for (int kt2 = 0; kt2 < 4; kt2++)
            #pragma unroll
            for (int r = 0; r < 16; r++)
                mx = fmaxf(mx, s[kt2][r]);
        mx = fmaxf(mx, __shfl_xor(mx, 32, 64));
        float mnew = fmaxf(m_run, mx);
        float corr = __builtin_amdgcn_exp2f(m_run - mnew);
        m_run = mnew;

        float psum = 0.f;
        #pragma unroll
        for (int kt2 = 0; kt2 < 4; kt2++)
            #pragma unroll
            for (int r = 0; r < 16; r++){
                float p = __builtin_amdgcn_exp2f(s[kt2][r] - mnew);
                s[kt2][r] = p;
                psum += p;
            }
        psum += __shfl_xor(psum, 32, 64);
        l_run = l_run * corr + psum;
        oacc[0] *= corr;
        oacc[1] *= corr;

        // ---- pack P -> bf16 B-fragments pa[ks = kt2*2+c]: lane needs P[q][key=16ks+8hi+j]
        bf16x8 pa[8];
        #pragma unroll
        for (int kt2 = 0; kt2 < 4; kt2++){
            #pragma unroll
            for (int c = 0; c < 2; c++){
                int base = 8 * c;
                uint32_t a0 = cvtpk_bf16(s[kt2][base + 0], s[kt2][base + 1]);
                uint32_t a1 = cvtpk_bf16(s[kt2][base + 2], s[kt2][base + 3]);
                uint32_t b0 = cvtpk_bf16(s[kt2][base + 4], s[kt2][base + 5]);
                uint32_t b1 = cvtpk_bf16(s[kt2][base + 6], s[kt2][base + 7]);
                uint32_t sa0 = (uint32_t)__shfl_xor((int)a0, 32, 64);
                uint32_t sa1 = (uint32_t)__shfl_xor((int)a1, 32, 64);
                uint32_t sb0 = (uint32_t)__shfl_xor((int)b0, 32, 64);
                uint32_t sb1 = (uint32_t)__shfl_xor((int)b1, 32, 64);
                uint32_t w0 = hi ? sb0 : a0;
                uint32_t w1 = hi ? sb1 : a1;
                uint32_t w2 = hi ? b0 : sa0;
                uint32_t w3 = hi ? b1 : sa1;
                uint32_t frag[4] = {w0, w1, w2, w3};
                pa[kt2 * 2 + c] = *(bf16x8*)frag;
            }
        }

        // ---- PV: O^T[et] += sum_ks mfma(A = Vt frag, B = pa[ks])
        #pragma unroll
        for (int et = 0; et < 2; et++){
            #pragma unroll
            for (int ks = 0; ks < 8; ks++){
                bf16x8 vf = *(const bf16x8*)(Vc + et * 8192 + ks * 1024 + lane * 16);
                oacc[et] = __builtin_amdgcn_mfma_f32_32x32x16_bf16(vf, pa[ks], oacc[et], 0, 0, 0);
            }
        }

        __syncthreads();           // vmcnt(0)+lgkmcnt(0) drain: next tile staged, reads done
        buf ^= 1;
    }

    // ---- normalize + store: lane q = q0+ql; e = et*32 + 8g + 4hi + m
    float inv = 1.0f / l_run;
    #pragma unroll
    for (int et = 0; et < 2; et++){
        #pragma unroll
        for (int g = 0; g < 4; g++){
            ushort4 o4;
            o4.x = f2b(oacc[et][4 * g + 0] * inv);
            o4.y = f2b(oacc[et][4 * g + 1] * inv);
            o4.z = f2b(oacc[et][4 * g + 2] * inv);
            o4.w = f2b(oacc[et][4 * g + 3] * inv);
            int e = et * 32 + 8 * g + 4 * hi;
            *(ushort4*)(ob + (size_t)(q0 + ql) * 1024 + (h << 6) + e) = o4;
        }
    }
}

// ---------------- launcher ----------------

extern "C" void kernel_launch(void* const* d_in, const int* in_sizes, int n_in,
                              void* d_out, int out_size, void* d_ws, size_t ws_size,
                              hipStream_t stream){
    const float* x  = (const float*)d_in[0];
    const float* Wq = (const float*)d_in[1];
    const float* bq = (const float*)d_in[2];
    const float* Wk = (const float*)d_in[3];
    const float* bk = (const float*)d_in[4];
    const float* Wv = (const float*)d_in[5];
    const float* bv = (const float*)d_in[6];
    const float* sc = (const float*)d_in[7];
    const float* Wo = (const float*)d_in[8];
    const float* bo = (const float*)d_in[9];
    float* out = (float*)d_out;
    char* ws = (char*)d_ws;
    const size_t MB = 1u << 20;

    unsigned short* xb  = (unsigned short*)(ws + 0);        // 8 MB  [S][D] bf16
    unsigned short* ob  = xb;                               // alias: o reuses xb after GEMM1
    unsigned short* wt  = (unsigned short*)(ws + 8  * MB);  // 6 MB  [3072][1024]
    unsigned short* wot = (unsigned short*)(ws + 14 * MB);  // 2 MB  [1024][1024]
    unsigned short* qb  = (unsigned short*)(ws + 16 * MB);  // 8 MB  [H][S][E]
    unsigned short* kb  = (unsigned short*)(ws + 24 * MB);  // 8 MB  [H][S][E]
    unsigned short* vb  = (unsigned short*)(ws + 32 * MB);  // 8 MB  [H][E][S]

    k_conv_x <<<4096,  256, 0, stream>>>(x, xb, S_LEN * D_MOD);
    k_conv_w <<<12288, 256, 0, stream>>>(Wq, Wk, Wv, wt);
    k_conv_wo<<<4096,  256, 0, stream>>>(Wo, wot);

    k_gemm<0><<<dim3(48, 64), 256, 0, stream>>>(xb, wt, D_MOD, qb, kb, vb, bq, bk, bv, sc, nullptr, nullptr);
    k_attn   <<<dim3(32, 16), 256, 0, stream>>>(qb, kb, vb, ob);
    k_gemm<1><<<dim3(16, 64), 256, 0, stream>>>(ob, wot, D_MOD, nullptr, nullptr, nullptr,
                                                nullptr, nullptr, nullptr, nullptr, out, bo);
}